// Round 20
// baseline (462.259 us; speedup 1.0000x reference)
//
#include <hip/hip_runtime.h>
#include <hip/hip_bf16.h>

#define NN 50000
#define NE 800000
#define IND 128
#define NH 8
#define EBLK 256          // binning blocks
#define EPB 3125          // NE / EBLK
#define NBUK 391          // buckets of 128 dst nodes
#define NBUKP 392         // padded (bucket 391 empty -> offset == NE)
#define GH (NBUKP * EBLK) // 100352

typedef __hip_bfloat16 bf16;
typedef __attribute__((ext_vector_type(8))) short short8;
typedef __attribute__((ext_vector_type(8))) __bf16 bf16x8;
typedef __attribute__((ext_vector_type(4))) float floatx4;
typedef __attribute__((ext_vector_type(2))) float floatx2;

static __device__ __forceinline__ short f2bf_bits(float f) {
    unsigned u = __float_as_uint(f);
    u = (u + 0x7fffu + ((u >> 16) & 1u)) >> 16;
    return (short)u;
}
static __device__ __forceinline__ float bf2f(bf16 v) { return __bfloat162float(v); }
static __device__ __forceinline__ floatx2 up2(unsigned av) {
    floatx2 r;
    r.x = __uint_as_float(av << 16);
    r.y = __uint_as_float(av & 0xffff0000u);
    return r;
}
static __device__ __forceinline__ unsigned pk2(float a, float b) {
    return (unsigned)(unsigned short)f2bf_bits(a) | ((unsigned)(unsigned short)f2bf_bits(b) << 16);
}

// ---------------- CSR build: two-level counting sort ----------------
__global__ __launch_bounds__(256) void bin_count_kernel(const int* __restrict__ edst,
        int* __restrict__ ghist) {
    __shared__ int h[NBUKP];
    const int tid = threadIdx.x, blk = blockIdx.x;
    for (int b = tid; b < NBUKP; b += 256) h[b] = 0;
    __syncthreads();
    const int e0 = blk * EPB;
    for (int e = e0 + tid; e < e0 + EPB; e += 256)
        atomicAdd(&h[edst[e] >> 7], 1);
    __syncthreads();
    for (int b = tid; b < NBUKP; b += 256)
        ghist[b * EBLK + blk] = h[b];
}
__global__ __launch_bounds__(256) void scang1_kernel(const int* __restrict__ src,
        int* __restrict__ pre, int* __restrict__ bsum, int n) {
    __shared__ int sh[256];
    const int tid = threadIdx.x;
    const int idx = blockIdx.x * 256 + tid;
    int c = (idx < n) ? src[idx] : 0;
    sh[tid] = c; __syncthreads();
    int val = c;
#pragma unroll
    for (int off = 1; off < 256; off <<= 1) {
        int t = (tid >= off) ? sh[tid - off] : 0;
        __syncthreads();
        val += t; sh[tid] = val;
        __syncthreads();
    }
    if (idx < n) pre[idx] = val - c;
    if (tid == 255) bsum[blockIdx.x] = val;
}
__global__ __launch_bounds__(512) void scang2_kernel(int* __restrict__ bsum, int nb) {
    __shared__ int sh[512];
    const int tid = threadIdx.x;
    int v = (tid < nb) ? bsum[tid] : 0;
    sh[tid] = v; __syncthreads();
    int val = v;
#pragma unroll
    for (int off = 1; off < 512; off <<= 1) {
        int t = (tid >= off) ? sh[tid - off] : 0;
        __syncthreads();
        val += t; sh[tid] = val;
        __syncthreads();
    }
    if (tid < nb) bsum[tid] = val - v;
}
__global__ __launch_bounds__(256) void bin_scatter_kernel(const int* __restrict__ esrc,
        const int* __restrict__ edst, const int* __restrict__ gpre,
        const int* __restrict__ gbsum, unsigned* __restrict__ ebuf) {
    __shared__ int cur[NBUKP];
    const int tid = threadIdx.x, blk = blockIdx.x;
    for (int b = tid; b < NBUKP; b += 256) {
        int i = b * EBLK + blk;
        cur[b] = gpre[i] + gbsum[i >> 8];
    }
    __syncthreads();
    const int e0 = blk * EPB;
    for (int e = e0 + tid; e < e0 + EPB; e += 256) {
        int d = edst[e], s = esrc[e];
        int pos = atomicAdd(&cur[d >> 7], 1);
        ebuf[pos] = ((unsigned)(d & 127) << 16) | (unsigned)s;
    }
}
__global__ __launch_bounds__(256) void bucket_finalize_kernel(const unsigned* __restrict__ ebuf,
        const int* __restrict__ gpre, const int* __restrict__ gbsum,
        int* __restrict__ rowptr, float* __restrict__ dinv, int* __restrict__ csrc) {
    __shared__ int lh[128], lcur[128], sc[256];
    const int bu = blockIdx.x, tid = threadIdx.x;
    const int seg_beg = gpre[bu * EBLK] + gbsum[bu];
    const int seg_end = gpre[(bu + 1) * EBLK] + gbsum[bu + 1];
    if (tid < 128) lh[tid] = 0;
    __syncthreads();
    for (int i = seg_beg + tid; i < seg_end; i += 256)
        atomicAdd(&lh[ebuf[i] >> 16], 1);
    __syncthreads();
    int c = (tid < 128) ? lh[tid] : 0;
    sc[tid] = c; __syncthreads();
    int val = c;
#pragma unroll
    for (int off = 1; off < 256; off <<= 1) {
        int t = (tid >= off) ? sc[tid - off] : 0;
        __syncthreads();
        val += t; sc[tid] = val;
        __syncthreads();
    }
    int excl = val - c;
    if (tid < 128) {
        lcur[tid] = excl;
        int node = bu * 128 + tid;
        if (node < NN) {
            rowptr[node] = seg_beg + excl;
            dinv[node] = rsqrtf((float)c + 1.f);
        }
    }
    if (bu == 0 && tid == 0) rowptr[NN] = NE;
    __syncthreads();
    for (int i = seg_beg + tid; i < seg_end; i += 256) {
        unsigned u = ebuf[i];
        int pos = atomicAdd(&lcur[u >> 16], 1);
        csrc[seg_beg + pos] = (int)(u & 0xffffu);
    }
}

// ---------------- merged weight prep (one launch; also zeroes cs1/cs2) ----------------
__global__ __launch_bounds__(256) void prep_all_kernel(
        const float* __restrict__ gcn1_w, const float* __restrict__ gcn2_w,
        const float* __restrict__ gat1_w, const float* __restrict__ gat2_w,
        const float* __restrict__ as1, const float* __restrict__ ad1,
        const float* __restrict__ as2, const float* __restrict__ ad2,
        bf16* __restrict__ wT1, bf16* __restrict__ wT2,
        bf16* __restrict__ wgT1, bf16* __restrict__ wgT2,
        float* __restrict__ was1, float* __restrict__ wad1,
        float* __restrict__ was2, float* __restrict__ wad2,
        float* __restrict__ cs1, float* __restrict__ cs2) {
    int idx = blockIdx.x * 256 + threadIdx.x;
    if (idx < 8192) {
        int m = idx >> 7, k = idx & 127;
        ((short*)wT1)[idx] = f2bf_bits(gcn1_w[(long)k * 64 + m]);
    } else if (idx < 12288) {
        int i = idx - 8192;
        int m = i >> 6, k = i & 63;
        ((short*)wT2)[i] = f2bf_bits(gcn2_w[(long)k * 64 + m]);
    } else if (idx < 45056) {
        int i = idx - 12288;
        int m = i >> 9, k = i & 511;
        int h = k >> 6, c = k & 63;
        ((short*)wgT1)[i] = f2bf_bits(gat1_w[(long)c * 512 + h * 64 + m]);
    } else if (idx < 77824) {
        int i = idx - 45056;
        int m = i >> 9, k = i & 511;
        int h = k >> 6, c = k & 63;
        ((short*)wgT2)[i] = (m < 32) ? f2bf_bits(gat2_w[(long)c * 256 + h * 32 + m]) : (short)0;
    } else if (idx < 78336) {
        int i = idx - 77824;
        int h = i >> 6, c = i & 63;
        const float* wrow = gat1_w + (long)c * 512 + h * 64;
        float s = 0.f, d = 0.f;
        for (int cc = 0; cc < 64; ++cc) {
            float w = wrow[cc];
            s += w * as1[h * 64 + cc];
            d += w * ad1[h * 64 + cc];
        }
        was1[i] = s; wad1[i] = d;
    } else if (idx < 78848) {
        int i = idx - 78336;
        int h = i >> 6, c = i & 63;
        const float* wrow = gat2_w + (long)c * 256 + h * 32;
        float s = 0.f, d = 0.f;
        for (int cc = 0; cc < 32; ++cc) {
            float w = wrow[cc];
            s += w * as2[h * 32 + cc];
            d += w * ad2[h * 32 + cc];
        }
        was2[i] = s; wad2[i] = d;
    } else if (idx < 78976) {
        int i = idx - 78848;
        if (i < 64) cs1[i] = 0.f; else cs2[i - 64] = 0.f;
    }
}

// ---------------- per-channel max of act (for u8 quant scales) ----------------
__global__ __launch_bounds__(256) void cmax_kernel(const bf16* __restrict__ actb,
        float* __restrict__ cs) {
    __shared__ float lmx[256];
    const int tid = threadIdx.x;
    const int c = tid & 63, g = tid >> 6;
    const int r0 = blockIdx.x * 512;
    float m = 0.f;
    for (int r = r0 + g; r < r0 + 512 && r < NN; r += 4)
        m = fmaxf(m, bf2f(actb[(long)r * 64 + c]));
    lmx[tid] = m;
    __syncthreads();
    if (tid < 64) {
        m = fmaxf(fmaxf(lmx[tid], lmx[tid + 64]), fmaxf(lmx[tid + 128], lmx[tid + 192]));
        atomicMax((unsigned*)cs + tid, __float_as_uint(m));   // act >= 0
    }
}

// ---------------- MFMA matmul v2: NO LDS ----------------
template<int K, int EPI, bool AF32>
__global__ __launch_bounds__(256) void mm2_kernel(const void* __restrict__ A,
        const bf16* __restrict__ wT, void* __restrict__ C,
        const float* __restrict__ bias, const float* __restrict__ rowscale,
        int nrows, int M) {
    const int row0 = blockIdx.x * 64;
    const int tid = threadIdx.x;
    const int lane = tid & 63, wave = tid >> 6;
    const int lr = lane & 15, q = lane >> 4;
    const int row = row0 + wave * 16 + lr;
    const bool rok = row < nrows;
    constexpr int NC = (EPI == 4) ? 2 : 4;
    floatx4 acc[NC] = {};
#pragma unroll 4
    for (int k0 = 0; k0 < K; k0 += 32) {
        short8 av = {0, 0, 0, 0, 0, 0, 0, 0};
        if (rok) {
            if (AF32) {
                const float* apf = (const float*)A + (long)row * K + q * 8 + k0;
                floatx4 va = *(const floatx4*)apf;
                floatx4 vb = *(const floatx4*)(apf + 4);
#pragma unroll
                for (int j = 0; j < 4; ++j) { av[j] = f2bf_bits(va[j]); av[4 + j] = f2bf_bits(vb[j]); }
            } else {
                av = *(const short8*)((const short*)A + (long)row * K + q * 8 + k0);
            }
        }
        bf16x8 a = __builtin_bit_cast(bf16x8, av);
#pragma unroll
        for (int c = 0; c < NC; ++c) {
            bf16x8 b = __builtin_bit_cast(bf16x8,
                *(const short8*)((const short*)wT + (long)(c * 16 + lr) * K + k0 + q * 8));
            acc[c] = __builtin_amdgcn_mfma_f32_16x16x32_bf16(a, b, acc[c], 0, 0, 0);
        }
    }
    if (EPI == 4) {
#pragma unroll
        for (int r = 0; r < 4; ++r) {
            int orow = row0 + wave * 16 + q * 4 + r;
            float v0 = acc[0][r] * 0.125f + bias[lr];
            float v1 = acc[1][r] * 0.125f + bias[16 + lr];
            float m = fmaxf(v0, v1);
#pragma unroll
            for (int off = 1; off < 16; off <<= 1) m = fmaxf(m, __shfl_xor(m, off));
            float s = __expf(v0 - m) + __expf(v1 - m);
#pragma unroll
            for (int off = 1; off < 16; off <<= 1) s += __shfl_xor(s, off);
            float ls = m + logf(s);
            if (orow < nrows) {
                ((float*)C)[(long)orow * 32 + lr] = v0 - ls;
                ((float*)C)[(long)orow * 32 + 16 + lr] = v1 - ls;
            }
        }
        return;
    }
#pragma unroll
    for (int c = 0; c < NC; ++c)
#pragma unroll
        for (int r = 0; r < 4; ++r) {
            int orow = row0 + wave * 16 + q * 4 + r;
            int col = c * 16 + lr;
            if (orow < nrows && col < M) {
                long o = (long)orow * M + col;
                float v = acc[c][r];
                if (EPI == 0) ((float*)C)[o] = v;
                else if (EPI == 2) {
                    v = v * 0.125f + bias[col];
                    ((bf16*)C)[o] = __float2bfloat16(fmaxf(v, 0.f));
                } else {
                    ((bf16*)C)[o] = __float2bfloat16(rowscale[orow] * v);
                }
            }
        }
}

// ---------------- fused GCN aggregate + bias + BN + ReLU ----------------
__global__ __launch_bounds__(256) void gcn_fused_kernel(const int* __restrict__ rowptr,
        const int* __restrict__ csrc, const float* __restrict__ dinv,
        const bf16* __restrict__ hin, const float* __restrict__ b,
        const float* __restrict__ gamma, const float* __restrict__ beta,
        const float* __restrict__ mean, const float* __restrict__ var,
        bf16* __restrict__ actout) {
    const int node = blockIdx.x * 4 + (threadIdx.x >> 6);
    if (node >= NN) return;
    const int lane = threadIdx.x & 63;
    const int eslot = lane >> 5, cp = lane & 31;
    const int beg = rowptr[node], end = rowptr[node + 1];
    const float di = dinv[node];
    floatx2 acc2 = {0.f, 0.f};
#pragma unroll 2
    for (int ei = beg + eslot; ei < end; ei += 2) {
        int s = csrc[ei];
        unsigned av = *(const unsigned*)((const unsigned short*)hin + (long)s * 64 + 2 * cp);
        acc2 += up2(av);
    }
    acc2.x += __shfl_xor(acc2.x, 32);
    acc2.y += __shfl_xor(acc2.y, 32);
    {
        unsigned sv = *(const unsigned*)((const unsigned short*)hin + (long)node * 64 + 2 * cp);
        acc2 += up2(sv);
    }
    int c0 = 2 * cp, c1 = c0 + 1;
    float x0 = acc2.x * di + b[c0];
    float x1 = acc2.y * di + b[c1];
    x0 = (x0 - mean[c0]) * rsqrtf(var[c0] + 1e-5f) * gamma[c0] + beta[c0];
    x1 = (x1 - mean[c1]) * rsqrtf(var[c1] + 1e-5f) * gamma[c1] + beta[c1];
    if (eslot == 0)
        *(unsigned*)((unsigned short*)actout + (long)node * 64 + c0) =
            pk2(fmaxf(x0, 0.f), fmaxf(x1, 0.f));
}

// es[n,h] (bf16) = <act[n,:], was[h,:]>; also emits per-channel u8 quantized act table
__global__ __launch_bounds__(256) void scores_kernel(const bf16* __restrict__ actb,
        const float* __restrict__ was, const float* __restrict__ wad,
        bf16* __restrict__ esb, float* __restrict__ ed,
        const float* __restrict__ cs, unsigned char* __restrict__ actq, int n) {
    const int node = blockIdx.x * 4 + (threadIdx.x >> 6);
    if (node >= n) return;
    const int lane = threadIdx.x & 63;
    const int h = lane >> 3, cg = lane & 7;
    short8 a8 = *(const short8*)((const short*)actb + (long)node * 64 + cg * 8);
    const float* wsp = was + h * 64 + cg * 8;
    const float* wdp = wad + h * 64 + cg * 8;
    floatx4 ws0 = *(const floatx4*)wsp, ws1 = *(const floatx4*)(wsp + 4);
    floatx4 wd0 = *(const floatx4*)wdp, wd1 = *(const floatx4*)(wdp + 4);
    float s = 0.f, d = 0.f;
    float av[8];
#pragma unroll
    for (int j = 0; j < 4; ++j) {
        float v0 = bf2f(__builtin_bit_cast(bf16, a8[j]));
        float v1 = bf2f(__builtin_bit_cast(bf16, a8[4 + j]));
        av[j] = v0; av[4 + j] = v1;
        s += v0 * ws0[j] + v1 * ws1[j];
        d += v0 * wd0[j] + v1 * wd1[j];
    }
#pragma unroll
    for (int off = 1; off < 8; off <<= 1) {
        s += __shfl_xor(s, off);
        d += __shfl_xor(d, off);
    }
    if (cg == 0) { esb[node * NH + h] = __float2bfloat16(s); ed[node * NH + h] = d; }
    // lanes h==0 (lane<8) quantize their 8 channels
    if (h == 0) {
        unsigned u0 = 0, u1 = 0;
#pragma unroll
        for (int j = 0; j < 8; ++j) {
            int c = cg * 8 + j;
            float qs = 255.f / fmaxf(cs[c], 1e-6f);
            int q = (int)(av[j] * qs + 0.5f);
            q = (q > 255) ? 255 : q;
            if (j < 4) u0 |= (unsigned)q << (8 * j);
            else       u1 |= (unsigned)q << (8 * (j - 4));
        }
        *(unsigned*)(actq + (long)node * 64 + cg * 8) = u0;
        *(unsigned*)(actq + (long)node * 64 + cg * 8 + 4) = u1;
    }
}

// ---------------- GAT aggregation (self-shifted softmax, u8 act gather) ----------------
// Working set: actq 3.2MB + esb 0.8MB ~= 4MB per-XCD L2 -> gather misses mostly eliminated.
__global__ __launch_bounds__(256) void gat_agg_kernel(const int* __restrict__ rowptr,
        const int* __restrict__ csrc, const bf16* __restrict__ esb, const float* __restrict__ ed,
        const unsigned char* __restrict__ actq, const float* __restrict__ cs,
        const bf16* __restrict__ actb, bf16* __restrict__ agg) {
    __shared__ __align__(16) float salpha[4][512];
    __shared__ int ssrcs[4][64];
    __shared__ __align__(16) float sself[4][8];
    const int wv = threadIdx.x >> 6;
    const int node = blockIdx.x * 4 + wv;
    if (node >= NN) return;
    const int lane = threadIdx.x & 63;
    const int h = lane & 7, slot = lane >> 3;
    const int beg = rowptr[node], end = rowptr[node + 1];
    const int deg = end - beg;
    const float edr = ed[node * NH + h];

    float selfe = bf2f(esb[node * NH + h]) + edr;
    selfe = selfe > 0.f ? selfe : 0.2f * selfe;

    if (deg <= 64) {
        // ---- Phase A: register-cached exps (self-shifted, exact) ----
        float ex_r[8]; int s_r[8];
        float den = 0.f;
#pragma unroll
        for (int b = 0; b < 8; ++b) {
            ex_r[b] = 0.f; s_r[b] = 0;
            int k = b * 8 + slot;
            if (k < deg) {
                int s = csrc[beg + k];
                s_r[b] = s;
                float e = bf2f(esb[s * NH + h]) + edr;
                e = e > 0.f ? e : 0.2f * e;
                ex_r[b] = __expf(e - selfe);
                den += ex_r[b];
            }
        }
        den += __shfl_xor(den, 8);
        den += __shfl_xor(den, 16);
        den += __shfl_xor(den, 32);
        const float invden = 1.f / (den + 1.f);

#pragma unroll
        for (int b = 0; b < 8; ++b)
            salpha[wv][b * 64 + lane] = ex_r[b] * invden;
        if (h == 0) {
#pragma unroll
            for (int b = 0; b < 8; ++b)
                ssrcs[wv][b * 8 + slot] = s_r[b];
        }
        if (slot == 0) sself[wv][h] = invden;

        // ---- Phase B: (head-quad, channel-pair) u8 gather ----
        const int hq = lane >> 5, cp = lane & 31;
        const float ds0 = cs[2 * cp] * (1.f / 255.f);
        const float ds1 = cs[2 * cp + 1] * (1.f / 255.f);
        floatx2 acc2[4] = {};
#pragma unroll 4
        for (int k = 0; k < deg; ++k) {
            int s = ssrcs[wv][k];
            unsigned short uv = *(const unsigned short*)(actq + (long)s * 64 + 2 * cp);
            floatx2 a2;
            a2.x = (float)(uv & 0xff) * ds0;
            a2.y = (float)(uv >> 8) * ds1;
            floatx4 al = *(const floatx4*)&salpha[wv][(k >> 3) * 64 + (k & 7) * 8 + hq * 4];
            acc2[0] += a2 * al[0]; acc2[1] += a2 * al[1];
            acc2[2] += a2 * al[2]; acc2[3] += a2 * al[3];
        }
        {   // self: exact bf16
            unsigned sv = *(const unsigned*)((const unsigned short*)actb + (long)node * 64 + 2 * cp);
            floatx2 a2 = up2(sv);
            floatx4 sa = *(const floatx4*)&sself[wv][hq * 4];
            acc2[0] += a2 * sa[0]; acc2[1] += a2 * sa[1];
            acc2[2] += a2 * sa[2]; acc2[3] += a2 * sa[3];
        }
#pragma unroll
        for (int j = 0; j < 4; ++j)
            *(unsigned*)((unsigned short*)agg + (long)node * 512 + (hq * 4 + j) * 64 + 2 * cp) =
                pk2(acc2[j].x, acc2[j].y);
    } else {
        // ---- fallback (deg>64, rare): streaming two-pass, bf16 act ----
        float acc[NH] = {0.f, 0.f, 0.f, 0.f, 0.f, 0.f, 0.f, 0.f};
        float den = 0.f;
        for (int base = beg; base < end; base += 8) {
            int ei = base + slot;
            if (ei < end) {
                int s = csrc[ei];
                float e = bf2f(esb[s * NH + h]) + edr;
                e = e > 0.f ? e : 0.2f * e;
                den += __expf(e - selfe);
            }
        }
        den += __shfl_xor(den, 8);
        den += __shfl_xor(den, 16);
        den += __shfl_xor(den, 32);
        const float invden = 1.f / (den + 1.f);
        for (int base = beg; base < end; base += 8) {
            int ei = base + slot;
            float al = 0.f; int sl = 0;
            if (ei < end) {
                sl = csrc[ei];
                float e = bf2f(esb[sl * NH + h]) + edr;
                e = e > 0.f ? e : 0.2f * e;
                al = __expf(e - selfe) * invden;
            }
            salpha[wv][lane] = al;
            if (h == 0) ssrcs[wv][slot] = sl;
            int ecnt = end - base; if (ecnt > 8) ecnt = 8;
            for (int j = 0; j < ecnt; ++j) {
                int s = ssrcs[wv][j];
                float a = bf2f(actb[(long)s * 64 + lane]);
                floatx4 al0 = *(const floatx4*)&salpha[wv][j * 8];
                floatx4 al1 = *(const floatx4*)&salpha[wv][j * 8 + 4];
                acc[0] += al0[0] * a; acc[1] += al0[1] * a;
                acc[2] += al0[2] * a; acc[3] += al0[3] * a;
                acc[4] += al1[0] * a; acc[5] += al1[1] * a;
                acc[6] += al1[2] * a; acc[7] += al1[3] * a;
            }
        }
        {
            if (slot == 0) sself[wv][h] = invden;
            float a = bf2f(actb[(long)node * 64 + lane]);
            floatx4 s0 = *(const floatx4*)&sself[wv][0];
            floatx4 s1 = *(const floatx4*)&sself[wv][4];
            acc[0] += s0[0] * a; acc[1] += s0[1] * a;
            acc[2] += s0[2] * a; acc[3] += s0[3] * a;
            acc[4] += s1[0] * a; acc[5] += s1[1] * a;
            acc[6] += s1[2] * a; acc[7] += s1[3] * a;
        }
#pragma unroll
        for (int hh = 0; hh < NH; ++hh)
            agg[(long)node * 512 + hh * 64 + lane] = __float2bfloat16(acc[hh]);
    }
}

// ---------------- launch ----------------
extern "C" void kernel_launch(void* const* d_in, const int* in_sizes, int n_in,
                              void* d_out, int out_size, void* d_ws, size_t ws_size,
                              hipStream_t stream) {
    const float* x        = (const float*)d_in[0];
    const int*   eidx     = (const int*)d_in[1];
    const float* gcn1_w   = (const float*)d_in[2];
    const float* gcn1_b   = (const float*)d_in[3];
    const float* bn1_g    = (const float*)d_in[4];
    const float* bn1_b    = (const float*)d_in[5];
    const float* bn1_m    = (const float*)d_in[6];
    const float* bn1_v    = (const float*)d_in[7];
    const float* gat1_w   = (const float*)d_in[8];
    const float* gat1_as  = (const float*)d_in[9];
    const float* gat1_ad  = (const float*)d_in[10];
    const float* gat1_b   = (const float*)d_in[11];
    const float* gcn2_w   = (const float*)d_in[12];
    const float* gcn2_b   = (const float*)d_in[13];
    const float* bn2_g    = (const float*)d_in[14];
    const float* bn2_b    = (const float*)d_in[15];
    const float* bn2_m    = (const float*)d_in[16];
    const float* bn2_v    = (const float*)d_in[17];
    const float* gat2_w   = (const float*)d_in[18];
    const float* gat2_as  = (const float*)d_in[19];
    const float* gat2_ad  = (const float*)d_in[20];
    const float* gat2_b   = (const float*)d_in[21];
    float* out = (float*)d_out;

    const int* esrc = eidx;
    const int* edst = eidx + NE;

    // workspace (~81 MB, < proven-safe 110.6 MB)
    float* ws = (float*)d_ws;
    int*      ghist  = (int*)ws;                        // GH
    int*      gpre   = ghist + GH;                      // GH
    int*      gbsum  = gpre + GH;                       // 512
    unsigned* ebuf   = (unsigned*)(gbsum + 512);        // NE
    int*      rowptr = (int*)(ebuf + NE);               // 50048
    int*      csrc   = rowptr + 50048;                  // NE
    float*    dinv   = (float*)(csrc + NE);             // 50048
    float*    ed     = dinv + 50048;                    // 400000
    float*    was1   = ed + 400000;                     // 512
    float*    wad1   = was1 + 512;                      // 512
    float*    was2   = wad1 + 512;                      // 512
    float*    wad2   = was2 + 512;                      // 512
    float*    cs1    = wad2 + 512;                      // 64
    float*    cs2    = cs1 + 64;                        // 64
    bf16*     esb    = (bf16*)(cs2 + 64);               // N*8 bf16
    bf16*     wT1    = esb + 400000;                    // 64*128
    bf16*     wT2    = wT1 + 64 * 128;                  // 64*64
    bf16*     wgT1   = wT2 + 64 * 64;                   // 64*512
    bf16*     wgT2   = wgT1 + 64 * 512;                 // 64*512
    bf16*     actb   = wgT2 + 64 * 512;                 // N*64 bf16
    bf16*     mmbf   = actb + (size_t)NN * 64;          // N*64 bf16
    bf16*     agg    = mmbf + (size_t)NN * 64;          // N*512 bf16
    unsigned char* actq = (unsigned char*)(agg + (size_t)NN * 512);  // N*64 u8

    auto cdiv = [](long a, long b) { return (int)((a + b - 1) / b); };
    const int GB = cdiv(NN, 64);
    const int NB = cdiv(NN, 4);
    const int CB = cdiv(NN, 512);

    // ---- CSR build ----
    bin_count_kernel<<<EBLK, 256, 0, stream>>>(edst, ghist);
    scang1_kernel<<<GH / 256, 256, 0, stream>>>(ghist, gpre, gbsum, GH);
    scang2_kernel<<<1, 512, 0, stream>>>(gbsum, GH / 256);
    bin_scatter_kernel<<<EBLK, 256, 0, stream>>>(esrc, edst, gpre, gbsum, ebuf);
    bucket_finalize_kernel<<<NBUK, 256, 0, stream>>>(ebuf, gpre, gbsum, rowptr, dinv, csrc);

    // ---- merged weight prep (+cs zero) ----
    prep_all_kernel<<<cdiv(78976, 256), 256, 0, stream>>>(
        gcn1_w, gcn2_w, gat1_w, gat2_w, gat1_as, gat1_ad, gat2_as, gat2_ad,
        wT1, wT2, wgT1, wgT2, was1, wad1, was2, wad2, cs1, cs2);

    // ---- GCN1 ----
    mm2_kernel<IND, 3, true><<<GB, 256, 0, stream>>>(x, wT1, mmbf, nullptr, dinv, NN, 64);
    gcn_fused_kernel<<<NB, 256, 0, stream>>>(rowptr, csrc, dinv, mmbf,
        gcn1_b, bn1_g, bn1_b, bn1_m, bn1_v, actb);

    // ---- GAT1 (C=64) ----
    cmax_kernel<<<CB, 256, 0, stream>>>(actb, cs1);
    scores_kernel<<<NB, 256, 0, stream>>>(actb, was1, wad1, esb, ed, cs1, actq, NN);
    gat_agg_kernel<<<NB, 256, 0, stream>>>(rowptr, csrc, esb, ed, actq, cs1, actb, agg);
    mm2_kernel<512, 2, false><<<GB, 256, 0, stream>>>(agg, wgT1, actb, gat1_b, nullptr, NN, 64);

    // ---- GCN2 ----
    mm2_kernel<64, 3, false><<<GB, 256, 0, stream>>>(actb, wT2, mmbf, nullptr, dinv, NN, 64);
    gcn_fused_kernel<<<NB, 256, 0, stream>>>(rowptr, csrc, dinv, mmbf,
        gcn2_b, bn2_g, bn2_b, bn2_m, bn2_v, actb);

    // ---- GAT2 (C=32) + fused log_softmax -> out ----
    cmax_kernel<<<CB, 256, 0, stream>>>(actb, cs2);
    scores_kernel<<<NB, 256, 0, stream>>>(actb, was2, wad2, esb, ed, cs2, actq, NN);
    gat_agg_kernel<<<NB, 256, 0, stream>>>(rowptr, csrc, esb, ed, actq, cs2, actb, agg);
    mm2_kernel<512, 4, false><<<GB, 256, 0, stream>>>(agg, wgT2, out, gat2_b, nullptr, NN, 32);
}

// Round 21
// 401.357 us; speedup vs baseline: 1.1517x; 1.1517x over previous
//
#include <hip/hip_runtime.h>
#include <hip/hip_bf16.h>

#define NN 50000
#define NE 800000
#define IND 128
#define NH 8
#define EBLK 256          // binning blocks
#define EPB 3125          // NE / EBLK
#define NBUK 391          // buckets of 128 dst nodes
#define NBUKP 392         // padded (bucket 391 empty -> offset == NE)
#define GH (NBUKP * EBLK) // 100352

typedef __hip_bfloat16 bf16;
typedef __attribute__((ext_vector_type(8))) short short8;
typedef __attribute__((ext_vector_type(8))) __bf16 bf16x8;
typedef __attribute__((ext_vector_type(4))) float floatx4;
typedef __attribute__((ext_vector_type(2))) float floatx2;

static __device__ __forceinline__ short f2bf_bits(float f) {
    unsigned u = __float_as_uint(f);
    u = (u + 0x7fffu + ((u >> 16) & 1u)) >> 16;
    return (short)u;
}
static __device__ __forceinline__ float bf2f(bf16 v) { return __bfloat162float(v); }
static __device__ __forceinline__ floatx2 up2(unsigned av) {
    floatx2 r;
    r.x = __uint_as_float(av << 16);
    r.y = __uint_as_float(av & 0xffff0000u);
    return r;
}
static __device__ __forceinline__ unsigned pk2(float a, float b) {
    return (unsigned)(unsigned short)f2bf_bits(a) | ((unsigned)(unsigned short)f2bf_bits(b) << 16);
}

// ---------------- CSR build: two-level counting sort ----------------
__global__ __launch_bounds__(256) void bin_count_kernel(const int* __restrict__ edst,
        int* __restrict__ ghist) {
    __shared__ int h[NBUKP];
    const int tid = threadIdx.x, blk = blockIdx.x;
    for (int b = tid; b < NBUKP; b += 256) h[b] = 0;
    __syncthreads();
    const int e0 = blk * EPB;
    for (int e = e0 + tid; e < e0 + EPB; e += 256)
        atomicAdd(&h[edst[e] >> 7], 1);
    __syncthreads();
    for (int b = tid; b < NBUKP; b += 256)
        ghist[b * EBLK + blk] = h[b];
}
__global__ __launch_bounds__(256) void scang1_kernel(const int* __restrict__ src,
        int* __restrict__ pre, int* __restrict__ bsum, int n) {
    __shared__ int sh[256];
    const int tid = threadIdx.x;
    const int idx = blockIdx.x * 256 + tid;
    int c = (idx < n) ? src[idx] : 0;
    sh[tid] = c; __syncthreads();
    int val = c;
#pragma unroll
    for (int off = 1; off < 256; off <<= 1) {
        int t = (tid >= off) ? sh[tid - off] : 0;
        __syncthreads();
        val += t; sh[tid] = val;
        __syncthreads();
    }
    if (idx < n) pre[idx] = val - c;
    if (tid == 255) bsum[blockIdx.x] = val;
}
__global__ __launch_bounds__(512) void scang2_kernel(int* __restrict__ bsum, int nb) {
    __shared__ int sh[512];
    const int tid = threadIdx.x;
    int v = (tid < nb) ? bsum[tid] : 0;
    sh[tid] = v; __syncthreads();
    int val = v;
#pragma unroll
    for (int off = 1; off < 512; off <<= 1) {
        int t = (tid >= off) ? sh[tid - off] : 0;
        __syncthreads();
        val += t; sh[tid] = val;
        __syncthreads();
    }
    if (tid < nb) bsum[tid] = val - v;
}
__global__ __launch_bounds__(256) void bin_scatter_kernel(const int* __restrict__ esrc,
        const int* __restrict__ edst, const int* __restrict__ gpre,
        const int* __restrict__ gbsum, unsigned* __restrict__ ebuf) {
    __shared__ int cur[NBUKP];
    const int tid = threadIdx.x, blk = blockIdx.x;
    for (int b = tid; b < NBUKP; b += 256) {
        int i = b * EBLK + blk;
        cur[b] = gpre[i] + gbsum[i >> 8];
    }
    __syncthreads();
    const int e0 = blk * EPB;
    for (int e = e0 + tid; e < e0 + EPB; e += 256) {
        int d = edst[e], s = esrc[e];
        int pos = atomicAdd(&cur[d >> 7], 1);
        ebuf[pos] = ((unsigned)(d & 127) << 16) | (unsigned)s;
    }
}
__global__ __launch_bounds__(256) void bucket_finalize_kernel(const unsigned* __restrict__ ebuf,
        const int* __restrict__ gpre, const int* __restrict__ gbsum,
        int* __restrict__ rowptr, float* __restrict__ dinv, int* __restrict__ csrc) {
    __shared__ int lh[128], lcur[128], sc[256];
    const int bu = blockIdx.x, tid = threadIdx.x;
    const int seg_beg = gpre[bu * EBLK] + gbsum[bu];
    const int seg_end = gpre[(bu + 1) * EBLK] + gbsum[bu + 1];
    if (tid < 128) lh[tid] = 0;
    __syncthreads();
    for (int i = seg_beg + tid; i < seg_end; i += 256)
        atomicAdd(&lh[ebuf[i] >> 16], 1);
    __syncthreads();
    int c = (tid < 128) ? lh[tid] : 0;
    sc[tid] = c; __syncthreads();
    int val = c;
#pragma unroll
    for (int off = 1; off < 256; off <<= 1) {
        int t = (tid >= off) ? sc[tid - off] : 0;
        __syncthreads();
        val += t; sc[tid] = val;
        __syncthreads();
    }
    int excl = val - c;
    if (tid < 128) {
        lcur[tid] = excl;
        int node = bu * 128 + tid;
        if (node < NN) {
            rowptr[node] = seg_beg + excl;
            dinv[node] = rsqrtf((float)c + 1.f);
        }
    }
    if (bu == 0 && tid == 0) rowptr[NN] = NE;
    __syncthreads();
    for (int i = seg_beg + tid; i < seg_end; i += 256) {
        unsigned u = ebuf[i];
        int pos = atomicAdd(&lcur[u >> 16], 1);
        csrc[seg_beg + pos] = (int)(u & 0xffffu);
    }
}

// ---------------- merged weight prep (one launch) ----------------
__global__ __launch_bounds__(256) void prep_all_kernel(
        const float* __restrict__ gcn1_w, const float* __restrict__ gcn2_w,
        const float* __restrict__ gat1_w, const float* __restrict__ gat2_w,
        const float* __restrict__ as1, const float* __restrict__ ad1,
        const float* __restrict__ as2, const float* __restrict__ ad2,
        bf16* __restrict__ wT1, bf16* __restrict__ wT2,
        bf16* __restrict__ wgT1, bf16* __restrict__ wgT2,
        float* __restrict__ was1, float* __restrict__ wad1,
        float* __restrict__ was2, float* __restrict__ wad2) {
    int idx = blockIdx.x * 256 + threadIdx.x;
    if (idx < 8192) {
        int m = idx >> 7, k = idx & 127;
        ((short*)wT1)[idx] = f2bf_bits(gcn1_w[(long)k * 64 + m]);
    } else if (idx < 12288) {
        int i = idx - 8192;
        int m = i >> 6, k = i & 63;
        ((short*)wT2)[i] = f2bf_bits(gcn2_w[(long)k * 64 + m]);
    } else if (idx < 45056) {
        int i = idx - 12288;
        int m = i >> 9, k = i & 511;
        int h = k >> 6, c = k & 63;
        ((short*)wgT1)[i] = f2bf_bits(gat1_w[(long)c * 512 + h * 64 + m]);
    } else if (idx < 77824) {
        int i = idx - 45056;
        int m = i >> 9, k = i & 511;
        int h = k >> 6, c = k & 63;
        ((short*)wgT2)[i] = (m < 32) ? f2bf_bits(gat2_w[(long)c * 256 + h * 32 + m]) : (short)0;
    } else if (idx < 78336) {
        int i = idx - 77824;
        int h = i >> 6, c = i & 63;
        const float* wrow = gat1_w + (long)c * 512 + h * 64;
        float s = 0.f, d = 0.f;
        for (int cc = 0; cc < 64; ++cc) {
            float w = wrow[cc];
            s += w * as1[h * 64 + cc];
            d += w * ad1[h * 64 + cc];
        }
        was1[i] = s; wad1[i] = d;
    } else if (idx < 78848) {
        int i = idx - 78336;
        int h = i >> 6, c = i & 63;
        const float* wrow = gat2_w + (long)c * 256 + h * 32;
        float s = 0.f, d = 0.f;
        for (int cc = 0; cc < 32; ++cc) {
            float w = wrow[cc];
            s += w * as2[h * 32 + cc];
            d += w * ad2[h * 32 + cc];
        }
        was2[i] = s; wad2[i] = d;
    }
}

// ---------------- MFMA matmul v2: NO LDS ----------------
template<int K, int EPI, bool AF32>
__global__ __launch_bounds__(256) void mm2_kernel(const void* __restrict__ A,
        const bf16* __restrict__ wT, void* __restrict__ C,
        const float* __restrict__ bias, const float* __restrict__ rowscale,
        int nrows, int M) {
    const int row0 = blockIdx.x * 64;
    const int tid = threadIdx.x;
    const int lane = tid & 63, wave = tid >> 6;
    const int lr = lane & 15, q = lane >> 4;
    const int row = row0 + wave * 16 + lr;
    const bool rok = row < nrows;
    constexpr int NC = (EPI == 4) ? 2 : 4;
    floatx4 acc[NC] = {};
#pragma unroll 4
    for (int k0 = 0; k0 < K; k0 += 32) {
        short8 av = {0, 0, 0, 0, 0, 0, 0, 0};
        if (rok) {
            if (AF32) {
                const float* apf = (const float*)A + (long)row * K + q * 8 + k0;
                floatx4 va = *(const floatx4*)apf;
                floatx4 vb = *(const floatx4*)(apf + 4);
#pragma unroll
                for (int j = 0; j < 4; ++j) { av[j] = f2bf_bits(va[j]); av[4 + j] = f2bf_bits(vb[j]); }
            } else {
                av = *(const short8*)((const short*)A + (long)row * K + q * 8 + k0);
            }
        }
        bf16x8 a = __builtin_bit_cast(bf16x8, av);
#pragma unroll
        for (int c = 0; c < NC; ++c) {
            bf16x8 b = __builtin_bit_cast(bf16x8,
                *(const short8*)((const short*)wT + (long)(c * 16 + lr) * K + k0 + q * 8));
            acc[c] = __builtin_amdgcn_mfma_f32_16x16x32_bf16(a, b, acc[c], 0, 0, 0);
        }
    }
    if (EPI == 4) {
#pragma unroll
        for (int r = 0; r < 4; ++r) {
            int orow = row0 + wave * 16 + q * 4 + r;
            float v0 = acc[0][r] * 0.125f + bias[lr];
            float v1 = acc[1][r] * 0.125f + bias[16 + lr];
            float m = fmaxf(v0, v1);
#pragma unroll
            for (int off = 1; off < 16; off <<= 1) m = fmaxf(m, __shfl_xor(m, off));
            float s = __expf(v0 - m) + __expf(v1 - m);
#pragma unroll
            for (int off = 1; off < 16; off <<= 1) s += __shfl_xor(s, off);
            float ls = m + logf(s);
            if (orow < nrows) {
                ((float*)C)[(long)orow * 32 + lr] = v0 - ls;
                ((float*)C)[(long)orow * 32 + 16 + lr] = v1 - ls;
            }
        }
        return;
    }
#pragma unroll
    for (int c = 0; c < NC; ++c)
#pragma unroll
        for (int r = 0; r < 4; ++r) {
            int orow = row0 + wave * 16 + q * 4 + r;
            int col = c * 16 + lr;
            if (orow < nrows && col < M) {
                long o = (long)orow * M + col;
                float v = acc[c][r];
                if (EPI == 0) ((float*)C)[o] = v;
                else if (EPI == 2) {
                    v = v * 0.125f + bias[col];
                    ((bf16*)C)[o] = __float2bfloat16(fmaxf(v, 0.f));
                } else {
                    ((bf16*)C)[o] = __float2bfloat16(rowscale[orow] * v);
                }
            }
        }
}

// ---------------- fused GCN aggregate + bias + BN + ReLU ----------------
__global__ __launch_bounds__(256) void gcn_fused_kernel(const int* __restrict__ rowptr,
        const int* __restrict__ csrc, const float* __restrict__ dinv,
        const bf16* __restrict__ hin, const float* __restrict__ b,
        const float* __restrict__ gamma, const float* __restrict__ beta,
        const float* __restrict__ mean, const float* __restrict__ var,
        bf16* __restrict__ actout) {
    const int node = blockIdx.x * 4 + (threadIdx.x >> 6);
    if (node >= NN) return;
    const int lane = threadIdx.x & 63;
    const int eslot = lane >> 5, cp = lane & 31;
    const int beg = rowptr[node], end = rowptr[node + 1];
    const float di = dinv[node];
    floatx2 acc2 = {0.f, 0.f};
#pragma unroll 2
    for (int ei = beg + eslot; ei < end; ei += 2) {
        int s = csrc[ei];
        unsigned av = *(const unsigned*)((const unsigned short*)hin + (long)s * 64 + 2 * cp);
        acc2 += up2(av);
    }
    acc2.x += __shfl_xor(acc2.x, 32);
    acc2.y += __shfl_xor(acc2.y, 32);
    {
        unsigned sv = *(const unsigned*)((const unsigned short*)hin + (long)node * 64 + 2 * cp);
        acc2 += up2(sv);
    }
    int c0 = 2 * cp, c1 = c0 + 1;
    float x0 = acc2.x * di + b[c0];
    float x1 = acc2.y * di + b[c1];
    x0 = (x0 - mean[c0]) * rsqrtf(var[c0] + 1e-5f) * gamma[c0] + beta[c0];
    x1 = (x1 - mean[c1]) * rsqrtf(var[c1] + 1e-5f) * gamma[c1] + beta[c1];
    if (eslot == 0)
        *(unsigned*)((unsigned short*)actout + (long)node * 64 + c0) =
            pk2(fmaxf(x0, 0.f), fmaxf(x1, 0.f));
}

// es[n,h] = <act[n,:], was[h,:]>
__global__ __launch_bounds__(256) void scores_kernel(const bf16* __restrict__ actb,
        const float* __restrict__ was, const float* __restrict__ wad,
        float* __restrict__ es, float* __restrict__ ed, int n) {
    const int node = blockIdx.x * 4 + (threadIdx.x >> 6);
    if (node >= n) return;
    const int lane = threadIdx.x & 63;
    const int h = lane >> 3, cg = lane & 7;
    short8 a8 = *(const short8*)((const short*)actb + (long)node * 64 + cg * 8);
    const float* wsp = was + h * 64 + cg * 8;
    const float* wdp = wad + h * 64 + cg * 8;
    floatx4 ws0 = *(const floatx4*)wsp, ws1 = *(const floatx4*)(wsp + 4);
    floatx4 wd0 = *(const floatx4*)wdp, wd1 = *(const floatx4*)(wdp + 4);
    float s = 0.f, d = 0.f;
#pragma unroll
    for (int j = 0; j < 4; ++j) {
        float v0 = bf2f(__builtin_bit_cast(bf16, a8[j]));
        float v1 = bf2f(__builtin_bit_cast(bf16, a8[4 + j]));
        s += v0 * ws0[j] + v1 * ws1[j];
        d += v0 * wd0[j] + v1 * wd1[j];
    }
#pragma unroll
    for (int off = 1; off < 8; off <<= 1) {
        s += __shfl_xor(s, off);
        d += __shfl_xor(d, off);
    }
    if (cg == 0) { es[node * NH + h] = s; ed[node * NH + h] = d; }
}

// ---------------- GAT aggregation (self-shifted softmax) ----------------
// Phase B lanes = (hq=lane>>5 head-quad, cp=lane&31 channel-pair).
__global__ __launch_bounds__(256) void gat_agg_kernel(const int* __restrict__ rowptr,
        const int* __restrict__ csrc, const float* __restrict__ es, const float* __restrict__ ed,
        const bf16* __restrict__ actb, bf16* __restrict__ agg) {
    __shared__ __align__(16) float salpha[4][512];
    __shared__ int ssrcs[4][64];
    __shared__ __align__(16) float sself[4][8];
    const int wv = threadIdx.x >> 6;
    const int node = blockIdx.x * 4 + wv;
    if (node >= NN) return;
    const int lane = threadIdx.x & 63;
    const int h = lane & 7, slot = lane >> 3;
    const int beg = rowptr[node], end = rowptr[node + 1];
    const int deg = end - beg;
    const float edr = ed[node * NH + h];

    float selfe = es[node * NH + h] + edr;
    selfe = selfe > 0.f ? selfe : 0.2f * selfe;

    if (deg <= 64) {
        // ---- Phase A: register-cached exps (self-shifted, exact) ----
        float ex_r[8]; int s_r[8];
        float den = 0.f;
#pragma unroll
        for (int b = 0; b < 8; ++b) {
            ex_r[b] = 0.f; s_r[b] = 0;
            int k = b * 8 + slot;
            if (k < deg) {
                int s = csrc[beg + k];
                s_r[b] = s;
                float e = es[s * NH + h] + edr;
                e = e > 0.f ? e : 0.2f * e;
                ex_r[b] = __expf(e - selfe);
                den += ex_r[b];
            }
        }
        den += __shfl_xor(den, 8);
        den += __shfl_xor(den, 16);
        den += __shfl_xor(den, 32);
        const float invden = 1.f / (den + 1.f);

        // stage all alphas (alpha(k,h) at salpha[(k>>3)*64 + (k&7)*8 + h]) + srcs + self
#pragma unroll
        for (int b = 0; b < 8; ++b)
            salpha[wv][b * 64 + lane] = ex_r[b] * invden;
        if (h == 0) {
#pragma unroll
            for (int b = 0; b < 8; ++b)
                ssrcs[wv][b * 8 + slot] = s_r[b];
        }
        if (slot == 0) sself[wv][h] = invden;

        // ---- Phase B: (head-quad, channel-pair) gather ----
        const int hq = lane >> 5, cp = lane & 31;
        floatx2 acc2[4] = {};
#pragma unroll 4
        for (int k = 0; k < deg; ++k) {
            int s = ssrcs[wv][k];
            unsigned av = *(const unsigned*)((const unsigned short*)actb + (long)s * 64 + 2 * cp);
            floatx2 a2 = up2(av);
            floatx4 al = *(const floatx4*)&salpha[wv][(k >> 3) * 64 + (k & 7) * 8 + hq * 4];
            acc2[0] += a2 * al[0]; acc2[1] += a2 * al[1];
            acc2[2] += a2 * al[2]; acc2[3] += a2 * al[3];
        }
        {   // self
            unsigned sv = *(const unsigned*)((const unsigned short*)actb + (long)node * 64 + 2 * cp);
            floatx2 a2 = up2(sv);
            floatx4 sa = *(const floatx4*)&sself[wv][hq * 4];
            acc2[0] += a2 * sa[0]; acc2[1] += a2 * sa[1];
            acc2[2] += a2 * sa[2]; acc2[3] += a2 * sa[3];
        }
#pragma unroll
        for (int j = 0; j < 4; ++j)
            *(unsigned*)((unsigned short*)agg + (long)node * 512 + (hq * 4 + j) * 64 + 2 * cp) =
                pk2(acc2[j].x, acc2[j].y);
    } else {
        // ---- fallback (deg>64, rare): streaming two-pass, full-wave per edge ----
        float acc[NH] = {0.f, 0.f, 0.f, 0.f, 0.f, 0.f, 0.f, 0.f};
        float den = 0.f;
        for (int base = beg; base < end; base += 8) {
            int ei = base + slot;
            if (ei < end) {
                int s = csrc[ei];
                float e = es[s * NH + h] + edr;
                e = e > 0.f ? e : 0.2f * e;
                den += __expf(e - selfe);
            }
        }
        den += __shfl_xor(den, 8);
        den += __shfl_xor(den, 16);
        den += __shfl_xor(den, 32);
        const float invden = 1.f / (den + 1.f);
        for (int base = beg; base < end; base += 8) {
            int ei = base + slot;
            float al = 0.f; int sl = 0;
            if (ei < end) {
                sl = csrc[ei];
                float e = es[sl * NH + h] + edr;
                e = e > 0.f ? e : 0.2f * e;
                al = __expf(e - selfe) * invden;
            }
            salpha[wv][lane] = al;
            if (h == 0) ssrcs[wv][slot] = sl;
            int ecnt = end - base; if (ecnt > 8) ecnt = 8;
            for (int j = 0; j < ecnt; ++j) {
                int s = ssrcs[wv][j];
                float a = bf2f(actb[(long)s * 64 + lane]);
                floatx4 al0 = *(const floatx4*)&salpha[wv][j * 8];
                floatx4 al1 = *(const floatx4*)&salpha[wv][j * 8 + 4];
                acc[0] += al0[0] * a; acc[1] += al0[1] * a;
                acc[2] += al0[2] * a; acc[3] += al0[3] * a;
                acc[4] += al1[0] * a; acc[5] += al1[1] * a;
                acc[6] += al1[2] * a; acc[7] += al1[3] * a;
            }
        }
        {
            if (slot == 0) sself[wv][h] = invden;
            float a = bf2f(actb[(long)node * 64 + lane]);
            floatx4 s0 = *(const floatx4*)&sself[wv][0];
            floatx4 s1 = *(const floatx4*)&sself[wv][4];
            acc[0] += s0[0] * a; acc[1] += s0[1] * a;
            acc[2] += s0[2] * a; acc[3] += s0[3] * a;
            acc[4] += s1[0] * a; acc[5] += s1[1] * a;
            acc[6] += s1[2] * a; acc[7] += s1[3] * a;
        }
#pragma unroll
        for (int hh = 0; hh < NH; ++hh)
            agg[(long)node * 512 + hh * 64 + lane] = __float2bfloat16(acc[hh]);
    }
}

// ---------------- launch ----------------
extern "C" void kernel_launch(void* const* d_in, const int* in_sizes, int n_in,
                              void* d_out, int out_size, void* d_ws, size_t ws_size,
                              hipStream_t stream) {
    const float* x        = (const float*)d_in[0];
    const int*   eidx     = (const int*)d_in[1];
    const float* gcn1_w   = (const float*)d_in[2];
    const float* gcn1_b   = (const float*)d_in[3];
    const float* bn1_g    = (const float*)d_in[4];
    const float* bn1_b    = (const float*)d_in[5];
    const float* bn1_m    = (const float*)d_in[6];
    const float* bn1_v    = (const float*)d_in[7];
    const float* gat1_w   = (const float*)d_in[8];
    const float* gat1_as  = (const float*)d_in[9];
    const float* gat1_ad  = (const float*)d_in[10];
    const float* gat1_b   = (const float*)d_in[11];
    const float* gcn2_w   = (const float*)d_in[12];
    const float* gcn2_b   = (const float*)d_in[13];
    const float* bn2_g    = (const float*)d_in[14];
    const float* bn2_b    = (const float*)d_in[15];
    const float* bn2_m    = (const float*)d_in[16];
    const float* bn2_v    = (const float*)d_in[17];
    const float* gat2_w   = (const float*)d_in[18];
    const float* gat2_as  = (const float*)d_in[19];
    const float* gat2_ad  = (const float*)d_in[20];
    const float* gat2_b   = (const float*)d_in[21];
    float* out = (float*)d_out;

    const int* esrc = eidx;
    const int* edst = eidx + NE;

    // workspace (~78 MB, < proven-safe 110.6 MB)
    float* ws = (float*)d_ws;
    int*      ghist  = (int*)ws;                        // GH
    int*      gpre   = ghist + GH;                      // GH
    int*      gbsum  = gpre + GH;                       // 512
    unsigned* ebuf   = (unsigned*)(gbsum + 512);        // NE
    int*      rowptr = (int*)(ebuf + NE);               // 50048
    int*      csrc   = rowptr + 50048;                  // NE
    float*    dinv   = (float*)(csrc + NE);             // 50048
    float*    es     = dinv + 50048;                    // 400000
    float*    ed     = es + 400000;                     // 400000
    float*    was1   = ed + 400000;                     // 512
    float*    wad1   = was1 + 512;                      // 512
    float*    was2   = wad1 + 512;                      // 512
    float*    wad2   = was2 + 512;                      // 512
    bf16*     wT1    = (bf16*)(wad2 + 512);             // 64*128
    bf16*     wT2    = wT1 + 64 * 128;                  // 64*64
    bf16*     wgT1   = wT2 + 64 * 64;                   // 64*512
    bf16*     wgT2   = wgT1 + 64 * 512;                 // 64*512
    bf16*     actb   = wgT2 + 64 * 512;                 // N*64 bf16
    bf16*     mmbf   = actb + (size_t)NN * 64;          // N*64 bf16
    bf16*     agg    = mmbf + (size_t)NN * 64;          // N*512 bf16

    auto cdiv = [](long a, long b) { return (int)((a + b - 1) / b); };
    const int GB = cdiv(NN, 64);
    const int NB = cdiv(NN, 4);

    // ---- CSR build ----
    bin_count_kernel<<<EBLK, 256, 0, stream>>>(edst, ghist);
    scang1_kernel<<<GH / 256, 256, 0, stream>>>(ghist, gpre, gbsum, GH);
    scang2_kernel<<<1, 512, 0, stream>>>(gbsum, GH / 256);
    bin_scatter_kernel<<<EBLK, 256, 0, stream>>>(esrc, edst, gpre, gbsum, ebuf);
    bucket_finalize_kernel<<<NBUK, 256, 0, stream>>>(ebuf, gpre, gbsum, rowptr, dinv, csrc);

    // ---- merged weight prep ----
    prep_all_kernel<<<cdiv(78848, 256), 256, 0, stream>>>(
        gcn1_w, gcn2_w, gat1_w, gat2_w, gat1_as, gat1_ad, gat2_as, gat2_ad,
        wT1, wT2, wgT1, wgT2, was1, wad1, was2, wad2);

    // ---- GCN1 ----
    mm2_kernel<IND, 3, true><<<GB, 256, 0, stream>>>(x, wT1, mmbf, nullptr, dinv, NN, 64);
    gcn_fused_kernel<<<NB, 256, 0, stream>>>(rowptr, csrc, dinv, mmbf,
        gcn1_b, bn1_g, bn1_b, bn1_m, bn1_v, actb);

    // ---- GAT1 (C=64) ----
    scores_kernel<<<NB, 256, 0, stream>>>(actb, was1, wad1, es, ed, NN);
    gat_agg_kernel<<<NB, 256, 0, stream>>>(rowptr, csrc, es, ed, actb, agg);
    mm2_kernel<512, 2, false><<<GB, 256, 0, stream>>>(agg, wgT1, actb, gat1_b, nullptr, NN, 64);

    // ---- GCN2 ----
    mm2_kernel<64, 3, false><<<GB, 256, 0, stream>>>(actb, wT2, mmbf, nullptr, dinv, NN, 64);
    gcn_fused_kernel<<<NB, 256, 0, stream>>>(rowptr, csrc, dinv, mmbf,
        gcn2_b, bn2_g, bn2_b, bn2_m, bn2_v, actb);

    // ---- GAT2 (C=32) + fused log_softmax -> out ----
    scores_kernel<<<NB, 256, 0, stream>>>(actb, was2, wad2, es, ed, NN);
    gat_agg_kernel<<<NB, 256, 0, stream>>>(rowptr, csrc, es, ed, actb, agg);
    mm2_kernel<512, 4, false><<<GB, 256, 0, stream>>>(agg, wgT2, out, gat2_b, nullptr, NN, 32);
}